// Round 4
// baseline (271.578 us; speedup 1.0000x reference)
//
#include <hip/hip_runtime.h>
#include <math.h>

// ForwardWarpStereo — gather formulation (no atomics), packed-fp32 inner loop.
// flow = (-disp, 0), disp in [0,40): output t receives only from sources
// x in [t-1, t+47]; bilinear splat weight to t == max(0, 1-|xs-t|) (triangle)
//   = max(0, min(1+u, 1-u)),  u = xs-t   (avoids abs: VOP3P has neg, not abs).
// Valid iff floor(xs) in [0, W-2]; invalid sources get xs = -1e9 sentinel.
// disp.min() cancels (res is a ratio; occlu unweighted). Row H-1: res=0, occlu=1.
//
// Block = one image row. LDS transposed [s&7][s>>3] so candidate j reads
// row-const / col = tid+const (conflict-free, immediate offsets).
// Each thread owns K=8 outputs as 4 float2 accumulator sets -> v_pk_*_f32.

typedef float f32x2 __attribute__((ext_vector_type(2)));

constexpr int Bn = 4, Cn = 3, Hn = 1080, Wn = 1920;
constexpr int NT = 256;
constexpr int K = 8;
constexpr int NACT = Wn / K;       // 240 gather threads
constexpr int RS = 247;            // col stride; cols used 0..246
constexpr float K_LOG2 = 0.49978214f;  // log2(1.414)
constexpr float EPSV = 1e-6f;

__global__ __launch_bounds__(NT)
void fwarp_gather(const float* __restrict__ im,
                  const float* __restrict__ disp,
                  float* __restrict__ out) {
  __shared__ float  As[8 * RS];   // xs (or -1e9 sentinel)
  __shared__ float4 Cs[8 * RS];   // {r, g, b, w}

  const int tid = threadIdx.x;
  const int row = blockIdx.x;          // b*H + y
  const int b = row / Hn;
  const int y = row - b * Hn;
  const size_t HW = (size_t)Hn * Wn;
  const float* dR = disp + (size_t)row * Wn;
  const float* iR = im + (size_t)b * Cn * HW + (size_t)y * Wn;
  const bool live = (y < Hn - 1);

  if (live) {
    #pragma unroll
    for (int it = 0; it < 8; ++it) {
      int s = tid + it * NT;
      if (s < Wn) {
        float d  = dR[s];
        float xs = (float)s - d;
        float mf = floorf(xs);
        float w  = exp2f(K_LOG2 * d);          // 1.414^d
        bool valid = (mf >= 0.0f) && (mf <= (float)(Wn - 2));
        int idx = (s & 7) * RS + (s >> 3) + 1;
        As[idx] = valid ? xs : -1.0e9f;
        Cs[idx] = make_float4(iR[s], iR[HW + s], iR[2 * HW + s], w);
      }
    }
    // sentinels: s = -1 and s in [Wn, Wn+47]
    if (tid < 49) {
      int s = (tid == 48) ? -1 : (Wn + tid);
      int idx = (s & 7) * RS + (s >> 3) + 1;   // s=-1 -> row 7, col 0
      As[idx] = -1.0e9f;
      Cs[idx] = make_float4(0.0f, 0.0f, 0.0f, 0.0f);
    }
  }
  __syncthreads();

  f32x2 aR[4], aG[4], aB[4], aM[4], aC[4];
  #pragma unroll
  for (int p = 0; p < 4; ++p) {
    aR[p] = 0.0f; aG[p] = 0.0f; aB[p] = 0.0f; aM[p] = 0.0f; aC[p] = 0.0f;
  }

  const int tb = tid * K;
  const float tbf = (float)tb;

  if (live && tid < NACT) {
    #pragma unroll 7
    for (int j = 0; j < 49; ++j) {
      // source s = tb - 1 + j ; tb%8==0 so s&7=(j-1)&7, s>>3 = tid+((j-1)>>3)
      const int r8 = (j - 1) & 7;
      const int cl = tid + ((j - 1) >> 3) + 1;
      float  xs = As[r8 * RS + cl];
      float4 c  = Cs[r8 * RS + cl];
      const float xr = xs - tbf;
      #pragma unroll
      for (int p = 0; p < 4; ++p) {
        f32x2 u  = f32x2{xr, xr} - f32x2{(float)(2 * p), (float)(2 * p + 1)};
        f32x2 t1 = 1.0f + u;
        f32x2 t2 = 1.0f - u;
        f32x2 wt = __builtin_elementwise_max(
                       __builtin_elementwise_min(t1, t2), f32x2{0.0f, 0.0f});
        f32x2 f  = wt * c.w;
        aR[p] += f * c.x;
        aG[p] += f * c.y;
        aB[p] += f * c.z;
        aM[p] += f;
        aC[p] += wt;
      }
    }
  }

  if (tid < NACT) {
    float* oRes = out + (size_t)b * Cn * HW + (size_t)y * Wn + tb;
    float* oOcc = out + (size_t)Bn * Cn * HW + (size_t)row * Wn + tb;
    float rv[K], gv[K], bv[K], ov[K];
    #pragma unroll
    for (int p = 0; p < 4; ++p) {
      #pragma unroll
      for (int h = 0; h < 2; ++h) {
        float m   = fmaxf(aM[p][h], EPSV);
        float inv = __builtin_amdgcn_rcpf(m);
        rv[2 * p + h] = aR[p][h] * inv;
        gv[2 * p + h] = aG[p][h] * inv;
        bv[2 * p + h] = aB[p][h] * inv;
        ov[2 * p + h] = 1.0f - fminf(aC[p][h], 1.0f);
      }
    }
    float4* q;
    q = (float4*)oRes;
    q[0] = make_float4(rv[0], rv[1], rv[2], rv[3]);
    q[1] = make_float4(rv[4], rv[5], rv[6], rv[7]);
    q = (float4*)(oRes + HW);
    q[0] = make_float4(gv[0], gv[1], gv[2], gv[3]);
    q[1] = make_float4(gv[4], gv[5], gv[6], gv[7]);
    q = (float4*)(oRes + 2 * HW);
    q[0] = make_float4(bv[0], bv[1], bv[2], bv[3]);
    q[1] = make_float4(bv[4], bv[5], bv[6], bv[7]);
    q = (float4*)oOcc;
    q[0] = make_float4(ov[0], ov[1], ov[2], ov[3]);
    q[1] = make_float4(ov[4], ov[5], ov[6], ov[7]);
  }
}

extern "C" void kernel_launch(void* const* d_in, const int* in_sizes, int n_in,
                              void* d_out, int out_size, void* d_ws, size_t ws_size,
                              hipStream_t stream) {
  const float* im   = (const float*)d_in[0];
  const float* disp = (const float*)d_in[1];
  float* out = (float*)d_out;
  fwarp_gather<<<dim3(Bn * Hn), dim3(NT), 0, stream>>>(im, disp, out);
}